// Round 6
// baseline (337.232 us; speedup 1.0000x reference)
//
#include <hip/hip_runtime.h>

// ---------------------------------------------------------------------------
// SelfAttention: GN -> 1x1 QKV -> softmax attention (N=4096) -> proj -> +x.
// v5: v4b minus the LDS union.  EMPIRICAL LAW (r1-r5): effective per-CU LDS
// pool for block co-residency is 64 KB -- 2 blocks resident only if
// LDS/block <= 32 KB.  v4b's 35.3 KB union dropped attn to 1 block/CU and
// 2.6x'd its runtime.  Winner-phase proj now reads wo as bf16 (wob, converted
// once in gn_stats) straight from global; attn LDS = 24.6 KB again.
// ---------------------------------------------------------------------------

typedef float f32x4 __attribute__((ext_vector_type(4)));
typedef short short8 __attribute__((ext_vector_type(8)));
typedef _Float16 half8 __attribute__((ext_vector_type(8)));
typedef unsigned short ush;
typedef unsigned short ush4 __attribute__((ext_vector_type(4)));

__device__ __forceinline__ ush f2bf(float f) {
  unsigned u = __builtin_bit_cast(unsigned, f);
  u = (u + 0x7FFFu + ((u >> 16) & 1u)) >> 16;  // RNE
  return (ush)u;
}
__device__ __forceinline__ float bf2f(ush v) {
  unsigned u = ((unsigned)v) << 16;
  return __builtin_bit_cast(float, u);
}
// software f32 -> fp8 e4m3fn (RNE), clamped
__device__ __forceinline__ unsigned f2fp8(float x) {
  unsigned u = __builtin_bit_cast(unsigned, x);
  unsigned s = (u >> 24) & 0x80u;
  unsigned au = u & 0x7fffffffu;
  if (au < 0x3A800000u) return s;              // |x| < 2^-10 -> 0
  if (au >= 0x43E00000u) return s | 0x7Eu;     // >= 448 -> clamp
  int e = (int)(au >> 23) - 127;
  if (e < -6) {                                // subnormal target, grid 2^-9
    float a = __builtin_bit_cast(float, au);
    int m = (int)(a * 512.0f + 0.5f);
    if (m >= 8) return s | 0x08u;
    return s | (unsigned)m;
  }
  unsigned keep = au >> 20, rem = au & 0xFFFFFu;
  keep += (rem > 0x80000u) || ((rem == 0x80000u) && (keep & 1u));
  int ef = (int)(keep >> 3) - 127;
  if (ef >= 8 && ((ef > 8) || ((keep & 7u) == 7u))) return s | 0x7Eu;
  return s | (unsigned)(((ef + 7) << 3) | (int)(keep & 7u));
}
__device__ __forceinline__ void async16(const void* g, void* l) {
  __builtin_amdgcn_global_load_lds(
      (const __attribute__((address_space(1))) unsigned int*)g,
      (__attribute__((address_space(3))) unsigned int*)l, 16, 0, 0);
}

// ---------------------------------------------------------------------------
// Kernel 1: GroupNorm stats -> per-channel scale/shift; blocks 0..15 also
// convert wo (f32) -> wob (bf16) for the fused proj phase in attn.
// ---------------------------------------------------------------------------
__global__ __launch_bounds__(256) void gn_stats_kernel(
    const float* __restrict__ x, const float* __restrict__ gamma,
    const float* __restrict__ beta, const float* __restrict__ wo,
    float* __restrict__ scale_c, float* __restrict__ shift_c,
    ush* __restrict__ wob) {
  int bg = blockIdx.x;  // b*32 + g
  int b = bg >> 5, g = bg & 31;
  int tid = threadIdx.x;
  if (bg < 16) {  // wo -> bf16 copy (16 blocks x 256 threads x 4 elems)
    int v4 = (bg * 256 + tid) * 4;
    float4 w4 = *(const float4*)(wo + v4);
    ush4 pk;
    pk.x = f2bf(w4.x); pk.y = f2bf(w4.y);
    pk.z = f2bf(w4.z); pk.w = f2bf(w4.w);
    *(ush4*)(wob + v4) = pk;
  }
  const float4* base = (const float4*)(x + (size_t)bg * 16384);
  float s = 0.f, sq = 0.f;
#pragma unroll
  for (int p = 0; p < 16; ++p) {
    float4 v = base[p * 256 + tid];
    s += (v.x + v.y) + (v.z + v.w);
    sq += (v.x * v.x + v.y * v.y) + (v.z * v.z + v.w * v.w);
  }
#pragma unroll
  for (int off = 32; off > 0; off >>= 1) {
    s += __shfl_down(s, off);
    sq += __shfl_down(sq, off);
  }
  __shared__ float rs[4], rq[4], mv[2];
  int w = tid >> 6, lane = tid & 63;
  if (lane == 0) { rs[w] = s; rq[w] = sq; }
  __syncthreads();
  if (tid == 0) {
    float S = (rs[0] + rs[1]) + (rs[2] + rs[3]);
    float Q = (rq[0] + rq[1]) + (rq[2] + rq[3]);
    float mean = S * (1.f / 16384.f);
    float var = Q * (1.f / 16384.f) - mean * mean;
    mv[0] = mean;
    mv[1] = rsqrtf(var + 1e-6f);
  }
  __syncthreads();
  if (tid < 4) {
    int c = (g << 2) + tid;
    float sc = mv[1] * gamma[c];
    scale_c[(b << 7) + c] = sc;
    shift_c[(b << 7) + c] = beta[c] - mv[0] * sc;
  }
}

// ---------------------------------------------------------------------------
// Kernel 2: QKV 1x1 convs via MFMA.  grid 1536 = type(3) x b(8) x itile(64).
// Outputs: Qt8[b][i][d] fp8 (scale = log2e/sqrt(128) folded -> softmax via
// exp2), Kt8[b][j][d] fp8, Vh[b][d][j] f16.
// ---------------------------------------------------------------------------
__global__ __launch_bounds__(256) void qkv_kernel(
    const float* __restrict__ x, const float* __restrict__ scale_c,
    const float* __restrict__ shift_c, const float* __restrict__ wq,
    const float* __restrict__ wk, const float* __restrict__ wv,
    const float* __restrict__ bq, const float* __restrict__ bk,
    const float* __restrict__ bv, char* __restrict__ Qt8,
    char* __restrict__ Kt8, _Float16* __restrict__ Vh) {
  __shared__ __align__(16) ush hs[64 * 136];    // h^T tile, pitch 272B, swizzled
  __shared__ __align__(16) ush wol[128 * 136];  // weight [o][c] bf16
  char* hs8 = (char*)hs;
  int bx = blockIdx.x;
  int type = bx >> 9;  // 0=Q,1=K,2=V
  int rb = bx & 511;
  int b = rb >> 6, i0 = (rb & 63) << 6;
  int tid = threadIdx.x;
  int w = tid >> 6, lane = tid & 63, ln15 = lane & 15, quad = lane >> 4;

  // stage normalized h^T tile: cell = (i, g8) = 4 channels, b64 swizzled write
#pragma unroll
  for (int p = 0; p < 8; ++p) {
    int id = p * 256 + tid;
    int i = id & 63;
    int g8 = id >> 6;
    int c0 = g8 << 2;
    const float* xp = x + (((size_t)((b << 7) + c0)) << 12) + i0 + i;
    ush4 pk4;
#pragma unroll
    for (int e = 0; e < 4; ++e) {
      float h = xp[(size_t)e << 12] * scale_c[(b << 7) + c0 + e] +
                shift_c[(b << 7) + c0 + e];
      pk4[e] = f2bf(h);
    }
    int pg = g8 ^ ((i & 15) << 1);
    *(ush4*)(hs8 + i * 272 + pg * 8) = pk4;
  }
  const float* W = type == 0 ? wq : (type == 1 ? wk : wv);
#pragma unroll
  for (int p = 0; p < 16; ++p) {
    int v = p * 256 + tid;
    int o = v >> 5, cv = (v & 31) << 2;
    float4 w4 = *(const float4*)(W + (o << 7) + cv);
    uint2 pk;
    pk.x = (unsigned)f2bf(w4.x) | ((unsigned)f2bf(w4.y) << 16);
    pk.y = (unsigned)f2bf(w4.z) | ((unsigned)f2bf(w4.w) << 16);
    *(uint2*)&wol[o * 136 + cv] = pk;
  }
  __syncthreads();

#define HS_FRAG(row, dc) \
  (*(const short8*)(hs8 + (row) * 272 + (((((dc)*4 + quad)) ^ ((row)&15)) << 4)))

  if (type < 2) {
    f32x4 acc[8] = {};
    int hrow = w * 16 + ln15;
#pragma unroll
    for (int dc = 0; dc < 4; ++dc) {
      short8 af = HS_FRAG(hrow, dc);
#pragma unroll
      for (int nb = 0; nb < 8; ++nb) {
        short8 bf = *(const short8*)&wol[(nb * 16 + ln15) * 136 + dc * 32 + quad * 8];
        acc[nb] = __builtin_amdgcn_mfma_f32_16x16x32_bf16(af, bf, acc[nb], 0, 0, 0);
      }
    }
    const float* bias = type == 0 ? bq : bk;
    char* dst8 = type == 0 ? Qt8 : Kt8;
    __syncthreads();  // hs reads done; reuse as bounce [i 64][o 128] pitch 144
#pragma unroll
    for (int nb = 0; nb < 8; ++nb) {
      int o = nb * 16 + ln15;
      float bi = bias[o];
#pragma unroll
      for (int r = 0; r < 4; ++r) {
        float val = acc[nb][r] + bi;
        if (type == 0) val *= 0.12751742f;  // log2(e)/sqrt(128)
        hs8[(w * 16 + quad * 4 + r) * 144 + o] = (char)f2fp8(val);
      }
    }
    __syncthreads();
    int i = tid >> 2, seg = tid & 3;
    uint4 d0 = *(const uint4*)(hs8 + i * 144 + seg * 32);
    uint4 d1 = *(const uint4*)(hs8 + i * 144 + seg * 32 + 16);
    char* drow = dst8 + (((size_t)((b << 12) + i0 + i)) << 7) + seg * 32;
    *(uint4*)drow = d0;
    *(uint4*)(drow + 16) = d1;
  } else {
    f32x4 acc[8] = {};
    int hrow = w * 16 + ln15;
#pragma unroll
    for (int dc = 0; dc < 4; ++dc) {
      short8 bf = HS_FRAG(hrow, dc);
#pragma unroll
      for (int mb = 0; mb < 8; ++mb) {
        short8 af = *(const short8*)&wol[(mb * 16 + ln15) * 136 + dc * 32 + quad * 8];
        acc[mb] = __builtin_amdgcn_mfma_f32_16x16x32_bf16(af, bf, acc[mb], 0, 0, 0);
      }
    }
#pragma unroll
    for (int mb = 0; mb < 8; ++mb) {
#pragma unroll
      for (int r = 0; r < 4; ++r) {
        int o = mb * 16 + quad * 4 + r;
        float val = acc[mb][r] + bv[o];
        Vh[(((size_t)((b << 7) + o)) << 12) + i0 + w * 16 + ln15] = (_Float16)val;
      }
    }
  }
#undef HS_FRAG
}

// ---------------------------------------------------------------------------
// Kernel 3: flash attention + fused proj (last-block-done gate).
// grid 512 = b(8) x qt(16) x ks(4); 4 waves, 64 q/wave; 32 key-tiles of 32.
// LDS = 24.6 KB (<= 32 KB keeps 2 blocks/CU -- see v5 header note).
// K-row permutation puts P directly in the B-layout of mfma_f32_16x16x32_f16
// (32 PV MFMAs/iter, b128 V reads).  Winner phase reads wob bf16 from global.
// ---------------------------------------------------------------------------
__global__ __launch_bounds__(256, 2) void attn_kernel(
    const char* __restrict__ Qt8, const char* __restrict__ Kt8,
    const _Float16* __restrict__ Vh, const float* __restrict__ x,
    const ush* __restrict__ wob, const float* __restrict__ bo,
    ush* __restrict__ po, float* __restrict__ lw, int* __restrict__ cnt,
    float* __restrict__ out) {
  __shared__ __align__(16) char ksb[2][4096];      // [j32][d128] fp8 swizzled
  __shared__ __align__(16) _Float16 vsb[2][4096];  // [d128][j32] f16 swizzled
  __shared__ int winflag;
  int bx = blockIdx.x;
  int b = bx & 7, qt = (bx >> 3) & 15, ksid = bx >> 7;
  int tid = threadIdx.x;
  int w = tid >> 6, lane = tid & 63, ln15 = lane & 15, quad = lane >> 4;
  int qbase = (qt << 8) + (w << 6);
  int j0 = ksid << 10;

  // Q fp8 fragments (B-operand: n=i, k=quad*8+j) straight from global
  long qf[4][4];
#pragma unroll
  for (int ih = 0; ih < 4; ++ih) {
    const char* qrow =
        Qt8 + (((size_t)((b << 12) + qbase + ih * 16 + ln15)) << 7);
#pragma unroll
    for (int dc = 0; dc < 4; ++dc)
      qf[ih][dc] = *(const long*)(qrow + dc * 32 + quad * 8);
  }

  // DMA source mappings (swizzle folded into per-lane source address)
  int kj = (w << 3) + (lane >> 3);  // K tile row this lane feeds
  int kh = (kj & 3) | (((kj >> 3) & 1) << 2);
  int kg = (lane & 7) ^ kh;
  const char* ksrc = Kt8 + (((size_t)((b << 12) + j0 + kj)) << 7) + (kg << 4);
  int d0r = (w << 5) + (lane >> 2);  // V rows this lane feeds (cc=0 / cc=1)
  int d1r = d0r + 16;
  int vg0 = (lane & 3) ^ (((d0r >> 1) + (d0r >> 3)) & 3);
  int vg1 = (lane & 3) ^ (((d1r >> 1) + (d1r >> 3)) & 3);
  const _Float16* vsrc0 =
      Vh + (((size_t)((b << 7) + d0r)) << 12) + j0 + (vg0 << 3);
  const _Float16* vsrc1 =
      Vh + (((size_t)((b << 7) + d1r)) << 12) + j0 + (vg1 << 3);
  char* kdA = &ksb[0][0] + (w << 10);
  char* kdB = &ksb[1][0] + (w << 10);
  char* vdA0 = (char*)&vsb[0][0] + ((w * 2 + 0) << 10);
  char* vdA1 = (char*)&vsb[0][0] + ((w * 2 + 1) << 10);
  char* vdB0 = (char*)&vsb[1][0] + ((w * 2 + 0) << 10);
  char* vdB1 = (char*)&vsb[1][0] + ((w * 2 + 1) << 10);

  // stage tile 0 into buf 0
  async16(ksrc, kdA);
  async16(vsrc0, vdA0);
  async16(vsrc1, vdA1);
  __syncthreads();

  f32x4 O[4][8] = {};  // O^T: [ih(i)][nb(d-block)]
  float lsum[4] = {0.f, 0.f, 0.f, 0.f};
  // permuted K rows for the S A-operand + their (shared) group hash
  int r0 = ((ln15 >> 2) << 3) + (ln15 & 3), r1 = r0 + 4;
  int hr = (ln15 & 3) | (((ln15 >> 2) & 1) << 2);

  for (int jt = 0; jt < 32; ++jt) {
    int buf = jt & 1;
    if (jt + 1 < 32) {
      ksrc += 4096;
      vsrc0 += 32;
      vsrc1 += 32;
      if (buf == 0) {
        async16(ksrc, kdB);
        async16(vsrc0, vdB0);
        async16(vsrc1, vdB1);
      } else {
        async16(ksrc, kdA);
        async16(vsrc0, vdA0);
        async16(vsrc1, vdA1);
      }
    }
    const char* kb = &ksb[buf][0];
    const char* vb = (const char*)&vsb[buf][0];

    // S^T = K(permuted rows) . Q   (fp8 MFMA, 32/iter)
    f32x4 S[4][2] = {};
#pragma unroll
    for (int dc = 0; dc < 4; ++dc) {
      int goff = ((((dc * 2 + (quad >> 1))) ^ hr) << 4) + ((quad & 1) << 3);
      long kf0 = *(const long*)(kb + r0 * 128 + goff);
      long kf1 = *(const long*)(kb + r1 * 128 + goff);
#pragma unroll
      for (int ih = 0; ih < 4; ++ih) {
        S[ih][0] = __builtin_amdgcn_mfma_f32_16x16x32_fp8_fp8(kf0, qf[ih][dc], S[ih][0], 0, 0, 0);
        S[ih][1] = __builtin_amdgcn_mfma_f32_16x16x32_fp8_fp8(kf1, qf[ih][dc], S[ih][1], 0, 0, 0);
      }
    }
    // exp2 -> f16; tile0 regs = k 0..3, tile1 regs = k 4..7 of the B-operand
    half8 pf[4];
#pragma unroll
    for (int ih = 0; ih < 4; ++ih) {
      float ls = 0.f;
      half8 p;
#pragma unroll
      for (int t = 0; t < 2; ++t)
#pragma unroll
        for (int r = 0; r < 4; ++r) {
          float pv = __builtin_amdgcn_exp2f(S[ih][t][r] - 7.2134752f);
          ls += pv;
          p[t * 4 + r] = (_Float16)pv;
        }
      pf[ih] = p;
      lsum[ih] += ls;
    }
    // O^T += V . P   (f16 K=32 MFMA, 32/iter; V frag = one b128)
#pragma unroll
    for (int nb = 0; nb < 8; ++nb) {
      int d = nb * 16 + ln15;
      int sd = ((d >> 1) + (d >> 3)) & 3;
      half8 vf = *(const half8*)(vb + d * 64 + ((quad ^ sd) << 4));
#pragma unroll
      for (int ih = 0; ih < 4; ++ih)
        O[ih][nb] = __builtin_amdgcn_mfma_f32_16x16x32_f16(vf, pf[ih], O[ih][nb], 0, 0, 0);
    }
    __syncthreads();  // drains DMA + tile handoff
  }

  // epilogue: unnormalized partial O^T -> po[ks][b][i][d], row-sums -> lw
#pragma unroll
  for (int ih = 0; ih < 4; ++ih) {
    float l = lsum[ih];
    l += __shfl_xor(l, 16);
    l += __shfl_xor(l, 32);
    if (quad == 0) lw[(ksid << 15) + (b << 12) + qbase + ih * 16 + ln15] = l;
    int i = qbase + ih * 16 + ln15;
    size_t rowb = (((size_t)((ksid * 8 + b)) << 12) + i) << 7;
#pragma unroll
    for (int nb = 0; nb < 8; ++nb) {
      ush4 pk;
      pk.x = f2bf(O[ih][nb][0]);
      pk.y = f2bf(O[ih][nb][1]);
      pk.z = f2bf(O[ih][nb][2]);
      pk.w = f2bf(O[ih][nb][3]);
      *(ush4*)(po + rowb + nb * 16 + quad * 4) = pk;
    }
  }

  // ---- last-block-done gate: 4th finisher per (b,qt) does the proj slab ----
  __threadfence();
  if (tid == 0) winflag = atomicAdd(&cnt[(b << 4) + qt], 1);
  __syncthreads();
  if (winflag != 3) return;
  __threadfence();

  int iw0 = (qt << 8) + (w << 6);
  for (int ic = 0; ic < 4; ++ic) {
    int i = iw0 + ic * 16 + ln15;
    float rl = 0.f;
#pragma unroll
    for (int s = 0; s < 4; ++s) rl += lw[(s << 15) + (b << 12) + i];
    float rinv = 1.f / rl;
    f32x4 acc[8] = {};
#pragma unroll
    for (int dc = 0; dc < 4; ++dc) {
      float vsum[8] = {0.f, 0.f, 0.f, 0.f, 0.f, 0.f, 0.f, 0.f};
#pragma unroll
      for (int s = 0; s < 4; ++s) {
        short8 pv = *(const short8*)(po + (((size_t)(s * 8 + b)) << 19) +
                                     ((size_t)i << 7) + dc * 32 + quad * 8);
#pragma unroll
        for (int e = 0; e < 8; ++e) vsum[e] += bf2f((ush)pv[e]);
      }
      short8 bfv;
#pragma unroll
      for (int e = 0; e < 8; ++e) bfv[e] = (short)f2bf(vsum[e] * rinv);
#pragma unroll
      for (int mb = 0; mb < 8; ++mb) {
        // wo A-fragment straight from global bf16 copy (L2-hot, 16B loads)
        short8 af = *(const short8*)(wob + ((mb * 16 + ln15) << 7) + dc * 32 +
                                     quad * 8);
        acc[mb] = __builtin_amdgcn_mfma_f32_16x16x32_bf16(af, bfv, acc[mb], 0, 0, 0);
      }
    }
#pragma unroll
    for (int mb = 0; mb < 8; ++mb) {
#pragma unroll
      for (int r = 0; r < 4; ++r) {
        int o = mb * 16 + quad * 4 + r;
        size_t idx = (((size_t)((b << 7) + o)) << 12) + i;
        out[idx] = x[idx] + acc[mb][r] + bo[o];
      }
    }
  }
}

// ---------------------------------------------------------------------------
extern "C" void kernel_launch(void* const* d_in, const int* in_sizes, int n_in,
                              void* d_out, int out_size, void* d_ws,
                              size_t ws_size, hipStream_t stream) {
  const float* x = (const float*)d_in[0];
  const float* gamma = (const float*)d_in[1];
  const float* beta = (const float*)d_in[2];
  const float* wq = (const float*)d_in[3];
  const float* bq = (const float*)d_in[4];
  const float* wk = (const float*)d_in[5];
  const float* bk = (const float*)d_in[6];
  const float* wv = (const float*)d_in[7];
  const float* bv = (const float*)d_in[8];
  const float* wo = (const float*)d_in[9];
  const float* bo = (const float*)d_in[10];
  float* out = (float*)d_out;

  const size_t NE = (size_t)8 * 4096 * 128;  // 4M elements
  char* Qt8 = (char*)d_ws;               // fp8 Q^T [b][i][d]   (4MB)
  char* Kt8 = Qt8 + NE;                  // fp8 K^T [b][j][d]   (4MB)
  _Float16* Vh = (_Float16*)(Kt8 + NE);  // f16 V [b][d][j]     (8MB)
  ush* po = (ush*)(Vh + NE);             // bf16 partial O [4][b][i][d] (32MB)
  float* lwp = (float*)(po + 4 * NE);    // f32 partial l [4][b][i] (512KB)
  float* scale_c = lwp + 4 * 32768;
  float* shift_c = scale_c + 1024;
  int* cnt = (int*)(shift_c + 1024);     // 128 gate counters
  ush* wob = (ush*)(cnt + 128);          // bf16 wo copy [o][c] (32KB)

  (void)hipMemsetAsync(cnt, 0, 128 * sizeof(int), stream);
  gn_stats_kernel<<<256, 256, 0, stream>>>(x, gamma, beta, wo, scale_c,
                                           shift_c, wob);
  qkv_kernel<<<1536, 256, 0, stream>>>(x, scale_c, shift_c, wq, wk, wv, bq, bk,
                                       bv, Qt8, Kt8, Vh);
  attn_kernel<<<512, 256, 0, stream>>>(Qt8, Kt8, Vh, x, wob, bo, po, lwp, cnt,
                                       out);
}

// Round 8
// 197.557 us; speedup vs baseline: 1.7070x; 1.7070x over previous
//
#include <hip/hip_runtime.h>

// ---------------------------------------------------------------------------
// SelfAttention: GN -> 1x1 QKV -> softmax attention (N=4096) -> proj -> +x.
// v6b: = v6 with compile fix (bit_cast cvt_pkrtz's __fp16x2 result).
// v6: revert the fused-proj gate (r5/r6: device-fence + winner-tail diluted
// attn to ~11% on every pipe; LDS was NOT the cause).  Separate LDS-free proj
// kernel (reads bf16 wob).  K-loop: PV as one mfma_f32_16x16x32_f16 per
// d-block via K-row permutation, phase-exact swizzles, softmax shift folded
// into S accumulator INIT (-5*log2e), P packed via cvt_pkrtz.
// ---------------------------------------------------------------------------

typedef float f32x4 __attribute__((ext_vector_type(4)));
typedef short short8 __attribute__((ext_vector_type(8)));
typedef _Float16 half8 __attribute__((ext_vector_type(8)));
typedef _Float16 half2t __attribute__((ext_vector_type(2)));
typedef unsigned short ush;
typedef unsigned short ush4 __attribute__((ext_vector_type(4)));

__device__ __forceinline__ ush f2bf(float f) {
  unsigned u = __builtin_bit_cast(unsigned, f);
  u = (u + 0x7FFFu + ((u >> 16) & 1u)) >> 16;  // RNE
  return (ush)u;
}
__device__ __forceinline__ float bf2f(ush v) {
  unsigned u = ((unsigned)v) << 16;
  return __builtin_bit_cast(float, u);
}
// software f32 -> fp8 e4m3fn (RNE), clamped
__device__ __forceinline__ unsigned f2fp8(float x) {
  unsigned u = __builtin_bit_cast(unsigned, x);
  unsigned s = (u >> 24) & 0x80u;
  unsigned au = u & 0x7fffffffu;
  if (au < 0x3A800000u) return s;              // |x| < 2^-10 -> 0
  if (au >= 0x43E00000u) return s | 0x7Eu;     // >= 448 -> clamp
  int e = (int)(au >> 23) - 127;
  if (e < -6) {                                // subnormal target, grid 2^-9
    float a = __builtin_bit_cast(float, au);
    int m = (int)(a * 512.0f + 0.5f);
    if (m >= 8) return s | 0x08u;
    return s | (unsigned)m;
  }
  unsigned keep = au >> 20, rem = au & 0xFFFFFu;
  keep += (rem > 0x80000u) || ((rem == 0x80000u) && (keep & 1u));
  int ef = (int)(keep >> 3) - 127;
  if (ef >= 8 && ((ef > 8) || ((keep & 7u) == 7u))) return s | 0x7Eu;
  return s | (unsigned)(((ef + 7) << 3) | (int)(keep & 7u));
}
__device__ __forceinline__ void async16(const void* g, void* l) {
  __builtin_amdgcn_global_load_lds(
      (const __attribute__((address_space(1))) unsigned int*)g,
      (__attribute__((address_space(3))) unsigned int*)l, 16, 0, 0);
}

// ---------------------------------------------------------------------------
// Kernel 1: GroupNorm stats -> per-channel scale/shift; blocks 0..15 also
// convert wo (f32) -> wob (bf16) for proj.
// ---------------------------------------------------------------------------
__global__ __launch_bounds__(256) void gn_stats_kernel(
    const float* __restrict__ x, const float* __restrict__ gamma,
    const float* __restrict__ beta, const float* __restrict__ wo,
    float* __restrict__ scale_c, float* __restrict__ shift_c,
    ush* __restrict__ wob) {
  int bg = blockIdx.x;  // b*32 + g
  int b = bg >> 5, g = bg & 31;
  int tid = threadIdx.x;
  if (bg < 16) {  // wo -> bf16 copy
    int v4 = (bg * 256 + tid) * 4;
    float4 w4 = *(const float4*)(wo + v4);
    ush4 pk;
    pk.x = f2bf(w4.x); pk.y = f2bf(w4.y);
    pk.z = f2bf(w4.z); pk.w = f2bf(w4.w);
    *(ush4*)(wob + v4) = pk;
  }
  const float4* base = (const float4*)(x + (size_t)bg * 16384);
  float s = 0.f, sq = 0.f;
#pragma unroll
  for (int p = 0; p < 16; ++p) {
    float4 v = base[p * 256 + tid];
    s += (v.x + v.y) + (v.z + v.w);
    sq += (v.x * v.x + v.y * v.y) + (v.z * v.z + v.w * v.w);
  }
#pragma unroll
  for (int off = 32; off > 0; off >>= 1) {
    s += __shfl_down(s, off);
    sq += __shfl_down(sq, off);
  }
  __shared__ float rs[4], rq[4], mv[2];
  int w = tid >> 6, lane = tid & 63;
  if (lane == 0) { rs[w] = s; rq[w] = sq; }
  __syncthreads();
  if (tid == 0) {
    float S = (rs[0] + rs[1]) + (rs[2] + rs[3]);
    float Q = (rq[0] + rq[1]) + (rq[2] + rq[3]);
    float mean = S * (1.f / 16384.f);
    float var = Q * (1.f / 16384.f) - mean * mean;
    mv[0] = mean;
    mv[1] = rsqrtf(var + 1e-6f);
  }
  __syncthreads();
  if (tid < 4) {
    int c = (g << 2) + tid;
    float sc = mv[1] * gamma[c];
    scale_c[(b << 7) + c] = sc;
    shift_c[(b << 7) + c] = beta[c] - mv[0] * sc;
  }
}

// ---------------------------------------------------------------------------
// Kernel 2: QKV 1x1 convs via MFMA.  grid 1536 = type(3) x b(8) x itile(64).
// Outputs: Qt8[b][i][d] fp8 (scale = log2e/sqrt(128) folded), Kt8[b][j][d]
// fp8, Vh[b][d][j] f16.
// ---------------------------------------------------------------------------
__global__ __launch_bounds__(256) void qkv_kernel(
    const float* __restrict__ x, const float* __restrict__ scale_c,
    const float* __restrict__ shift_c, const float* __restrict__ wq,
    const float* __restrict__ wk, const float* __restrict__ wv,
    const float* __restrict__ bq, const float* __restrict__ bk,
    const float* __restrict__ bv, char* __restrict__ Qt8,
    char* __restrict__ Kt8, _Float16* __restrict__ Vh) {
  __shared__ __align__(16) ush hs[64 * 136];    // h^T tile, pitch 272B, swizzled
  __shared__ __align__(16) ush wol[128 * 136];  // weight [o][c] bf16
  char* hs8 = (char*)hs;
  int bx = blockIdx.x;
  int type = bx >> 9;  // 0=Q,1=K,2=V
  int rb = bx & 511;
  int b = rb >> 6, i0 = (rb & 63) << 6;
  int tid = threadIdx.x;
  int w = tid >> 6, lane = tid & 63, ln15 = lane & 15, quad = lane >> 4;

  // stage normalized h^T tile: cell = (i, g8) = 4 channels, b64 swizzled write
#pragma unroll
  for (int p = 0; p < 8; ++p) {
    int id = p * 256 + tid;
    int i = id & 63;
    int g8 = id >> 6;
    int c0 = g8 << 2;
    const float* xp = x + (((size_t)((b << 7) + c0)) << 12) + i0 + i;
    ush4 pk4;
#pragma unroll
    for (int e = 0; e < 4; ++e) {
      float h = xp[(size_t)e << 12] * scale_c[(b << 7) + c0 + e] +
                shift_c[(b << 7) + c0 + e];
      pk4[e] = f2bf(h);
    }
    int pg = g8 ^ ((i & 15) << 1);
    *(ush4*)(hs8 + i * 272 + pg * 8) = pk4;
  }
  const float* W = type == 0 ? wq : (type == 1 ? wk : wv);
#pragma unroll
  for (int p = 0; p < 16; ++p) {
    int v = p * 256 + tid;
    int o = v >> 5, cv = (v & 31) << 2;
    float4 w4 = *(const float4*)(W + (o << 7) + cv);
    uint2 pk;
    pk.x = (unsigned)f2bf(w4.x) | ((unsigned)f2bf(w4.y) << 16);
    pk.y = (unsigned)f2bf(w4.z) | ((unsigned)f2bf(w4.w) << 16);
    *(uint2*)&wol[o * 136 + cv] = pk;
  }
  __syncthreads();

#define HS_FRAG(row, dc) \
  (*(const short8*)(hs8 + (row) * 272 + (((((dc)*4 + quad)) ^ ((row)&15)) << 4)))

  if (type < 2) {
    f32x4 acc[8] = {};
    int hrow = w * 16 + ln15;
#pragma unroll
    for (int dc = 0; dc < 4; ++dc) {
      short8 af = HS_FRAG(hrow, dc);
#pragma unroll
      for (int nb = 0; nb < 8; ++nb) {
        short8 bf = *(const short8*)&wol[(nb * 16 + ln15) * 136 + dc * 32 + quad * 8];
        acc[nb] = __builtin_amdgcn_mfma_f32_16x16x32_bf16(af, bf, acc[nb], 0, 0, 0);
      }
    }
    const float* bias = type == 0 ? bq : bk;
    char* dst8 = type == 0 ? Qt8 : Kt8;
    __syncthreads();  // hs reads done; reuse as bounce [i 64][o 128] pitch 144
#pragma unroll
    for (int nb = 0; nb < 8; ++nb) {
      int o = nb * 16 + ln15;
      float bi = bias[o];
#pragma unroll
      for (int r = 0; r < 4; ++r) {
        float val = acc[nb][r] + bi;
        if (type == 0) val *= 0.12751742f;  // log2(e)/sqrt(128)
        hs8[(w * 16 + quad * 4 + r) * 144 + o] = (char)f2fp8(val);
      }
    }
    __syncthreads();
    int i = tid >> 2, seg = tid & 3;
    uint4 d0 = *(const uint4*)(hs8 + i * 144 + seg * 32);
    uint4 d1 = *(const uint4*)(hs8 + i * 144 + seg * 32 + 16);
    char* drow = dst8 + (((size_t)((b << 12) + i0 + i)) << 7) + seg * 32;
    *(uint4*)drow = d0;
    *(uint4*)(drow + 16) = d1;
  } else {
    f32x4 acc[8] = {};
    int hrow = w * 16 + ln15;
#pragma unroll
    for (int dc = 0; dc < 4; ++dc) {
      short8 bf = HS_FRAG(hrow, dc);
#pragma unroll
      for (int mb = 0; mb < 8; ++mb) {
        short8 af = *(const short8*)&wol[(mb * 16 + ln15) * 136 + dc * 32 + quad * 8];
        acc[mb] = __builtin_amdgcn_mfma_f32_16x16x32_bf16(af, bf, acc[mb], 0, 0, 0);
      }
    }
#pragma unroll
    for (int mb = 0; mb < 8; ++mb) {
#pragma unroll
      for (int r = 0; r < 4; ++r) {
        int o = mb * 16 + quad * 4 + r;
        float val = acc[mb][r] + bv[o];
        Vh[(((size_t)((b << 7) + o)) << 12) + i0 + w * 16 + ln15] = (_Float16)val;
      }
    }
  }
#undef HS_FRAG
}

// ---------------------------------------------------------------------------
// Kernel 3: flash attention, 4-way key split.  grid 512 = b(8) x qt(16) x
// ks(4); 4 waves, 64 q/wave; 32 key-tiles of 32.  LDS 24.6 KB, dbuf via
// global_load_lds with source-folded swizzles.  S accumulators INIT to
// -5*log2e (softmax shift for free); P packed with cvt_pkrtz; PV is one
// f16 K=32 MFMA per d-block (K-row permutation).  No gate, no fences.
// ---------------------------------------------------------------------------
__global__ __launch_bounds__(256, 2) void attn_kernel(
    const char* __restrict__ Qt8, const char* __restrict__ Kt8,
    const _Float16* __restrict__ Vh, ush* __restrict__ po,
    float* __restrict__ lw) {
  __shared__ __align__(16) char ksb[2][4096];      // [j32][d128] fp8 swizzled
  __shared__ __align__(16) _Float16 vsb[2][4096];  // [d128][j32] f16 swizzled
  int bx = blockIdx.x;
  int b = bx & 7, qt = (bx >> 3) & 15, ksid = bx >> 7;
  int tid = threadIdx.x;
  int w = tid >> 6, lane = tid & 63, ln15 = lane & 15, quad = lane >> 4;
  int qbase = (qt << 8) + (w << 6);
  int j0 = ksid << 10;

  // Q fp8 fragments (B-operand: n=i, k=quad*8+j) straight from global
  long qf[4][4];
#pragma unroll
  for (int ih = 0; ih < 4; ++ih) {
    const char* qrow =
        Qt8 + (((size_t)((b << 12) + qbase + ih * 16 + ln15)) << 7);
#pragma unroll
    for (int dc = 0; dc < 4; ++dc)
      qf[ih][dc] = *(const long*)(qrow + dc * 32 + quad * 8);
  }

  // DMA source mappings (swizzle folded into per-lane source address)
  int kj = (w << 3) + (lane >> 3);
  int kh = (kj & 3) | (((kj >> 3) & 1) << 2);
  int kg = (lane & 7) ^ kh;
  const char* ksrc = Kt8 + (((size_t)((b << 12) + j0 + kj)) << 7) + (kg << 4);
  int d0r = (w << 5) + (lane >> 2);
  int d1r = d0r + 16;
  int vg0 = (lane & 3) ^ (((d0r >> 1) + (d0r >> 3)) & 3);
  int vg1 = (lane & 3) ^ (((d1r >> 1) + (d1r >> 3)) & 3);
  const _Float16* vsrc0 =
      Vh + (((size_t)((b << 7) + d0r)) << 12) + j0 + (vg0 << 3);
  const _Float16* vsrc1 =
      Vh + (((size_t)((b << 7) + d1r)) << 12) + j0 + (vg1 << 3);
  char* kdA = &ksb[0][0] + (w << 10);
  char* kdB = &ksb[1][0] + (w << 10);
  char* vdA0 = (char*)&vsb[0][0] + ((w * 2 + 0) << 10);
  char* vdA1 = (char*)&vsb[0][0] + ((w * 2 + 1) << 10);
  char* vdB0 = (char*)&vsb[1][0] + ((w * 2 + 0) << 10);
  char* vdB1 = (char*)&vsb[1][0] + ((w * 2 + 1) << 10);

  // stage tile 0 into buf 0
  async16(ksrc, kdA);
  async16(vsrc0, vdA0);
  async16(vsrc1, vdA1);
  __syncthreads();

  f32x4 O[4][8] = {};  // O^T: [ih(i)][nb(d-block)]
  float lsum[4] = {0.f, 0.f, 0.f, 0.f};
  const f32x4 SINIT = {-7.2134752f, -7.2134752f, -7.2134752f, -7.2134752f};
  // permuted K rows for the S A-operand + their (shared) group hash
  int r0 = ((ln15 >> 2) << 3) + (ln15 & 3), r1 = r0 + 4;
  int hr = (ln15 & 3) | (((ln15 >> 2) & 1) << 2);

  for (int jt = 0; jt < 32; ++jt) {
    int buf = jt & 1;
    if (jt + 1 < 32) {
      ksrc += 4096;
      vsrc0 += 32;
      vsrc1 += 32;
      if (buf == 0) {
        async16(ksrc, kdB);
        async16(vsrc0, vdB0);
        async16(vsrc1, vdB1);
      } else {
        async16(ksrc, kdA);
        async16(vsrc0, vdA0);
        async16(vsrc1, vdA1);
      }
    }
    const char* kb = &ksb[buf][0];
    const char* vb = (const char*)&vsb[buf][0];

    // S^T = K(permuted rows) . Q  (fp8 MFMA, 32/iter; C-init = softmax shift)
    f32x4 S[4][2];
#pragma unroll
    for (int ih = 0; ih < 4; ++ih) { S[ih][0] = SINIT; S[ih][1] = SINIT; }
#pragma unroll
    for (int dc = 0; dc < 4; ++dc) {
      int goff = ((((dc * 2 + (quad >> 1))) ^ hr) << 4) + ((quad & 1) << 3);
      long kf0 = *(const long*)(kb + r0 * 128 + goff);
      long kf1 = *(const long*)(kb + r1 * 128 + goff);
#pragma unroll
      for (int ih = 0; ih < 4; ++ih) {
        S[ih][0] = __builtin_amdgcn_mfma_f32_16x16x32_fp8_fp8(kf0, qf[ih][dc], S[ih][0], 0, 0, 0);
        S[ih][1] = __builtin_amdgcn_mfma_f32_16x16x32_fp8_fp8(kf1, qf[ih][dc], S[ih][1], 0, 0, 0);
      }
    }
    // exp2 -> f16 (packed cvt); tile0 regs = k 0..3, tile1 = k 4..7
    half8 pf[4];
#pragma unroll
    for (int ih = 0; ih < 4; ++ih) {
      float ls = 0.f;
      half8 p;
#pragma unroll
      for (int t = 0; t < 2; ++t) {
        float p0 = __builtin_amdgcn_exp2f(S[ih][t][0]);
        float p1 = __builtin_amdgcn_exp2f(S[ih][t][1]);
        float p2 = __builtin_amdgcn_exp2f(S[ih][t][2]);
        float p3 = __builtin_amdgcn_exp2f(S[ih][t][3]);
        ls += (p0 + p1) + (p2 + p3);
        half2t h01 = __builtin_bit_cast(half2t, __builtin_amdgcn_cvt_pkrtz(p0, p1));
        half2t h23 = __builtin_bit_cast(half2t, __builtin_amdgcn_cvt_pkrtz(p2, p3));
        p[t * 4 + 0] = h01.x; p[t * 4 + 1] = h01.y;
        p[t * 4 + 2] = h23.x; p[t * 4 + 3] = h23.y;
      }
      pf[ih] = p;
      lsum[ih] += ls;
    }
    // O^T += V . P   (f16 K=32 MFMA, 32/iter; V frag = one b128)
#pragma unroll
    for (int nb = 0; nb < 8; ++nb) {
      int d = nb * 16 + ln15;
      int sd = ((d >> 1) + (d >> 3)) & 3;
      half8 vf = *(const half8*)(vb + d * 64 + ((quad ^ sd) << 4));
#pragma unroll
      for (int ih = 0; ih < 4; ++ih)
        O[ih][nb] = __builtin_amdgcn_mfma_f32_16x16x32_f16(vf, pf[ih], O[ih][nb], 0, 0, 0);
    }
    __syncthreads();  // drains DMA + tile handoff
  }

  // epilogue: unnormalized partial O^T -> po[ks][b][i][d], row-sums -> lw
#pragma unroll
  for (int ih = 0; ih < 4; ++ih) {
    float l = lsum[ih];
    l += __shfl_xor(l, 16);
    l += __shfl_xor(l, 32);
    if (quad == 0) lw[(ksid << 15) + (b << 12) + qbase + ih * 16 + ln15] = l;
    int i = qbase + ih * 16 + ln15;
    size_t rowb = (((size_t)((ksid * 8 + b)) << 12) + i) << 7;
#pragma unroll
    for (int nb = 0; nb < 8; ++nb) {
      ush4 pk;
      pk.x = f2bf(O[ih][nb][0]);
      pk.y = f2bf(O[ih][nb][1]);
      pk.z = f2bf(O[ih][nb][2]);
      pk.w = f2bf(O[ih][nb][3]);
      *(ush4*)(po + rowb + nb * 16 + quad * 4) = pk;
    }
  }
}

// ---------------------------------------------------------------------------
// Kernel 4: combine key-split partials + proj + bias + residual.
// grid 512 = (b, itile of 64); LDS-free (wo read as bf16 wob from L2).
// ---------------------------------------------------------------------------
__global__ __launch_bounds__(256) void proj_kernel(
    const float* __restrict__ x, const ush* __restrict__ po,
    const float* __restrict__ lw, const ush* __restrict__ wob,
    const float* __restrict__ bo, float* __restrict__ out) {
  int bx = blockIdx.x;
  int b = bx >> 6, i0 = (bx & 63) << 6;
  int tid = threadIdx.x;
  int w = tid >> 6, lane = tid & 63, ln15 = lane & 15, quad = lane >> 4;
  int i = i0 + w * 16 + ln15;
  float rl = 0.f;
#pragma unroll
  for (int s = 0; s < 4; ++s) rl += lw[(s << 15) + (b << 12) + i];
  float rinv = 1.f / rl;

  f32x4 acc[8] = {};
#pragma unroll
  for (int dc = 0; dc < 4; ++dc) {
    float vsum[8] = {0.f, 0.f, 0.f, 0.f, 0.f, 0.f, 0.f, 0.f};
#pragma unroll
    for (int s = 0; s < 4; ++s) {
      short8 pv = *(const short8*)(po + (((size_t)(s * 8 + b)) << 19) +
                                   ((size_t)i << 7) + dc * 32 + quad * 8);
#pragma unroll
      for (int e = 0; e < 8; ++e) vsum[e] += bf2f((ush)pv[e]);
    }
    short8 bfv;
#pragma unroll
    for (int e = 0; e < 8; ++e) bfv[e] = (short)f2bf(vsum[e] * rinv);
#pragma unroll
    for (int mb = 0; mb < 8; ++mb) {
      short8 af = *(const short8*)(wob + ((mb * 16 + ln15) << 7) + dc * 32 +
                                   quad * 8);
      acc[mb] = __builtin_amdgcn_mfma_f32_16x16x32_bf16(af, bfv, acc[mb], 0, 0, 0);
    }
  }
#pragma unroll
  for (int mb = 0; mb < 8; ++mb) {
#pragma unroll
    for (int r = 0; r < 4; ++r) {
      int o = mb * 16 + quad * 4 + r;
      size_t idx = (((size_t)(b << 7) + o) << 12) + i;
      out[idx] = x[idx] + acc[mb][r] + bo[o];
    }
  }
}

// ---------------------------------------------------------------------------
extern "C" void kernel_launch(void* const* d_in, const int* in_sizes, int n_in,
                              void* d_out, int out_size, void* d_ws,
                              size_t ws_size, hipStream_t stream) {
  const float* x = (const float*)d_in[0];
  const float* gamma = (const float*)d_in[1];
  const float* beta = (const float*)d_in[2];
  const float* wq = (const float*)d_in[3];
  const float* bq = (const float*)d_in[4];
  const float* wk = (const float*)d_in[5];
  const float* bk = (const float*)d_in[6];
  const float* wv = (const float*)d_in[7];
  const float* bv = (const float*)d_in[8];
  const float* wo = (const float*)d_in[9];
  const float* bo = (const float*)d_in[10];
  float* out = (float*)d_out;

  const size_t NE = (size_t)8 * 4096 * 128;  // 4M elements
  char* Qt8 = (char*)d_ws;               // fp8 Q^T [b][i][d]   (4MB)
  char* Kt8 = Qt8 + NE;                  // fp8 K^T [b][j][d]   (4MB)
  _Float16* Vh = (_Float16*)(Kt8 + NE);  // f16 V [b][d][j]     (8MB)
  ush* po = (ush*)(Vh + NE);             // bf16 partial O [4][b][i][d] (32MB)
  float* lwp = (float*)(po + 4 * NE);    // f32 partial l [4][b][i] (512KB)
  float* scale_c = lwp + 4 * 32768;
  float* shift_c = scale_c + 1024;
  ush* wob = (ush*)(shift_c + 1024);     // bf16 wo copy [o][c] (32KB)

  gn_stats_kernel<<<256, 256, 0, stream>>>(x, gamma, beta, wo, scale_c,
                                           shift_c, wob);
  qkv_kernel<<<1536, 256, 0, stream>>>(x, scale_c, shift_c, wq, wk, wv, bq, bk,
                                       bv, Qt8, Kt8, Vh);
  attn_kernel<<<512, 256, 0, stream>>>(Qt8, Kt8, Vh, po, lwp);
  proj_kernel<<<512, 256, 0, stream>>>(x, po, lwp, wob, bo, out);
}